// Round 1
// 344.795 us; speedup vs baseline: 1.0710x; 1.0710x over previous
//
#include <hip/hip_runtime.h>
#include <stdint.h>
#include <math.h>

// Problem constants (fixed by reference file)
#define NROWS 32768     // B*S = 8*4096
#define DIM   256
#define KCODES 8192
#define BETA  0.25f
#define RSPLIT 16       // rescue col-splits (512 cols each)
#define NELEM 8388608   // NROWS*DIM
// margin threshold: hi-only pair-error sigma ~5e-3; tau ~ 19 sigma. Rows with
// min2-min1 < tau (~1-2% by order-statistics of 8192 Gaussian scores) get an
// exact 3-term rescore via rescue_gemm.
#define TAU 0.09375f

typedef float f32x4 __attribute__((ext_vector_type(4)));
typedef _Float16 v8h __attribute__((ext_vector_type(8)));
typedef unsigned short us4 __attribute__((ext_vector_type(4)));

// ---------- fp16 two-term split (Ootomo): x ~= hi + lo ----------
__device__ inline unsigned int split1(float x) {
    _Float16 hf = (_Float16)x;
    _Float16 lf = (_Float16)(x - (float)hf);
    unsigned int h = __builtin_bit_cast(unsigned short, hf);
    unsigned int l = __builtin_bit_cast(unsigned short, lf);
    return h | (l << 16);
}

__device__ inline void gload_lds16(const void* g, void* l) {
    __builtin_amdgcn_global_load_lds(
        (const __attribute__((address_space(1))) void*)g,
        (__attribute__((address_space(3))) void*)l,
        16, 0, 0);
}

// float -> order-preserving uint32 (for packed atomicMin)
__device__ inline unsigned int fkey(float f) {
    unsigned int b = __float_as_uint(f);
    return (b & 0x80000000u) ? ~b : (b | 0x80000000u);
}

// ---------- fused prep: z-split, e-split, enrm, and zero counters ----------
__global__ void prep_all(const float* __restrict__ z,
                         const float* __restrict__ e,
                         unsigned short* __restrict__ zhi,
                         unsigned short* __restrict__ zlo,
                         unsigned short* __restrict__ ehi,
                         unsigned short* __restrict__ elo,
                         float* __restrict__ enrm,
                         float* __restrict__ counts,
                         float* __restrict__ lossAcc,
                         int* __restrict__ flagcnt) {
    if (blockIdx.x < 8192) {
        int t = blockIdx.x * 256 + threadIdx.x;   // float4 index
        float4 v = reinterpret_cast<const float4*>(z)[t];
        unsigned int p0 = split1(v.x);
        unsigned int p1 = split1(v.y);
        unsigned int p2 = split1(v.z);
        unsigned int p3 = split1(v.w);
        us4 h, l;
        h[0] = (unsigned short)p0; l[0] = (unsigned short)(p0 >> 16);
        h[1] = (unsigned short)p1; l[1] = (unsigned short)(p1 >> 16);
        h[2] = (unsigned short)p2; l[2] = (unsigned short)(p2 >> 16);
        h[3] = (unsigned short)p3; l[3] = (unsigned short)(p3 >> 16);
        reinterpret_cast<us4*>(zhi)[t] = h;
        reinterpret_cast<us4*>(zlo)[t] = l;
    } else {
        int row = blockIdx.x - 8192;
        int d = threadIdx.x;
        float x = e[(size_t)row * DIM + d];
        unsigned int p = split1(x);
        ehi[(size_t)row * DIM + d] = (unsigned short)p;
        elo[(size_t)row * DIM + d] = (unsigned short)(p >> 16);
        float sq = x * x;
        #pragma unroll
        for (int off = 32; off; off >>= 1) sq += __shfl_down(sq, off);
        __shared__ float ps[4];
        if ((threadIdx.x & 63) == 0) ps[threadIdx.x >> 6] = sq;
        __syncthreads();
        if (threadIdx.x == 0) {
            enrm[row] = 0.5f * (ps[0] + ps[1] + ps[2] + ps[3]);
            counts[row] = 0.f;
            if (row == 0) { *lossAcc = 0.f; *flagcnt = 0; }
        }
    }
}

// ---------- hi-only GEMM + per-row (min1, argmin1, min2) + margin flag ----------
// R10 structure: K=256 is tiny -> per-wave A panel register-resident (4 mi x
// 8 k-slabs x b128 = 128 VGPR, loaded once, direct from global: the 16x16x32
// A-fragment is 8 contiguous f16 per lane). LDS stages ONLY B: ring-4 16KB
// buffers, prefetch depth 3, counted s_waitcnt vmcnt(6) (never 0) + raw
// s_barrier pairs (T3/T4). Ring-4 => buffer index == bk == compile-time under
// the unrolled bk loop (no dynamic reg-array indexing). enrm lives in LDS so
// the main loop has NO vector-global loads besides stages (vmcnt ledger exact).
// CSPLIT=1: one block owns a full 128-row slab -> merge_flag fused into the
// epilogue. 512 thr / 8 waves (2M x 4N, 64x32 per wave), grid 256 = 1 blk/CU.
__launch_bounds__(512, 2)
__global__ void gemm_hi_fused(const unsigned short* __restrict__ zhi,
                              const unsigned short* __restrict__ ehi,
                              const float* __restrict__ enrm,
                              int* __restrict__ colidx,
                              float* __restrict__ out_idx,
                              int* __restrict__ flagcnt,
                              int* __restrict__ flaglist,
                              unsigned long long* __restrict__ rkey) {
    __shared__ __align__(16) unsigned short Bs[4][128 * 64];  // 64 KB B ring
    __shared__ float esL[KCODES];                             // 32 KB enrm
    __shared__ float rvv[4][128];
    __shared__ float rv2s[4][128];
    __shared__ int   rcc[4][128];

    const int tid = threadIdx.x;
    const int w = tid >> 6, l = tid & 63;
    const int lx = l & 15, quad = l >> 4;
    const int wm = w >> 2, wn = w & 3;          // 2M x 4N wave grid
    const int arow_base = blockIdx.x * 128;
    const int st_g = ((l & 7) ^ (l >> 3)) * 8;  // stage-source XOR swizzle
    const int fr_lx7 = lx & 7;

    // A fragments register-resident for the whole kernel (loaded once).
    // af[mi][ks] == zhi[row][ks*32 + quad*8 .. +8], row = base+mi*16+lx —
    // identical content to the old LDS-swizzled ds_read path.
    v8h af[4][8];
    #pragma unroll
    for (int mi = 0; mi < 4; ++mi) {
        const unsigned short* ap =
            zhi + (size_t)(arow_base + wm * 64 + mi * 16 + lx) * DIM + quad * 8;
        #pragma unroll
        for (int ks = 0; ks < 8; ++ks)
            af[mi][ks] = *(const v8h*)(ap + ks * 32);
    }

    // enrm -> LDS (plain linear; ds_read in epilogue counts lgkm, not vmcnt)
    #pragma unroll
    for (int j = 0; j < 4; ++j)
        gload_lds16(enrm + (j * 8 + w) * 256 + l * 4, &esL[(j * 8 + w) * 256]);

    // Stage one 128-col x 64-K B slab into ring buffer BUF.
    // Wave-uniform LDS dest (8 rows/wave/issue), per-lane pre-swizzled source.
#define STAGE(BUF, SN, AO) do {                                               \
        const unsigned short* _s0 =                                           \
            ehi + (size_t)((SN) * 128 + (tid >> 3)) * DIM + (AO) + st_g;      \
        gload_lds16(_s0, &Bs[BUF][(w * 8) * 64]);                             \
        gload_lds16(_s0 + (size_t)64 * DIM, &Bs[BUF][(64 + w * 8) * 64]);     \
    } while (0)

    // prologue: steps 0,1,2 (nt=0, bk=0/1/2)
    STAGE(0, 0, 0); STAGE(1, 0, 64); STAGE(2, 0, 128);

    float runv[16], runv2[16];
    int runc[16];
    #pragma unroll
    for (int s = 0; s < 16; ++s) {
        runv[s] = 3.0e38f; runv2[s] = 3.0e38f; runc[s] = 0x7fffffff;
    }

    for (int nt = 0; nt < 64; ++nt) {           // 64 N-tiles of 128 cols
        f32x4 acc[4][2];
        #pragma unroll
        for (int mi = 0; mi < 4; ++mi)
            #pragma unroll
            for (int ni = 0; ni < 2; ++ni) {
                f32x4 zz = {0.f, 0.f, 0.f, 0.f};
                acc[mi][ni] = zz;
            }

        #pragma unroll
        for (int bk = 0; bk < 4; ++bk) {        // step s = nt*4+bk, buf = bk
            // issue stage for step s+3 -> buf (bk+3)&3 (compile-time)
            const int sn = (bk == 0) ? nt : ((nt + 1) & 63);
            STAGE((bk + 3) & 3, sn, ((bk + 3) & 3) * 64);
            // counted wait: 4 stages (8 instrs) may be in flight; keep the 3
            // newest (6 instrs) in flight -> stage(s) is complete. Never 0.
            asm volatile("s_waitcnt vmcnt(6)" ::: "memory");
            __builtin_amdgcn_s_barrier();
            asm volatile("" ::: "memory");

            __builtin_amdgcn_s_setprio(1);
            #pragma unroll
            for (int kc = 0; kc < 2; ++kc) {
                const int gsw = ((kc * 4 + quad) ^ fr_lx7) * 8;
                v8h b0 = *(const v8h*)&Bs[bk][(wn * 32 + lx) * 64 + gsw];
                v8h b1 = *(const v8h*)&Bs[bk][(wn * 32 + 16 + lx) * 64 + gsw];
                #pragma unroll
                for (int mi = 0; mi < 4; ++mi) {
                    acc[mi][0] = __builtin_amdgcn_mfma_f32_16x16x32_f16(
                        af[mi][bk * 2 + kc], b0, acc[mi][0], 0, 0, 0);
                    acc[mi][1] = __builtin_amdgcn_mfma_f32_16x16x32_f16(
                        af[mi][bk * 2 + kc], b1, acc[mi][1], 0, 0, 0);
                }
            }
            __builtin_amdgcn_s_setprio(0);

            asm volatile("" ::: "memory");
            __builtin_amdgcn_s_barrier();
        }

        // epilogue outside the barrier-critical region (touches no Bs):
        // 2-min update, 5 VALU/elem (sub, med3, cmp, cndmask, min).
        const int cb = nt * 128 + wn * 32 + lx;
        #pragma unroll
        for (int ni = 0; ni < 2; ++ni) {
            const int col = cb + ni * 16;
            const float es = esL[col];
            #pragma unroll
            for (int mi = 0; mi < 4; ++mi)
                #pragma unroll
                for (int r = 0; r < 4; ++r) {
                    const int s = mi * 4 + r;
                    const float sv = es - acc[mi][ni][r];
                    const bool lt = sv < runv[s];
                    runv2[s] = __builtin_amdgcn_fmed3f(sv, runv[s], runv2[s]);
                    runc[s] = lt ? col : runc[s];
                    runv[s] = fminf(runv[s], sv);
                }
        }
    }
#undef STAGE

    // cross-lane reduce over the 16 lx lanes (16 cols of same row per slot)
    #pragma unroll
    for (int s = 0; s < 16; ++s) {
        float v1 = runv[s], v2 = runv2[s];
        int c1 = runc[s];
        #pragma unroll
        for (int m = 1; m < 16; m <<= 1) {
            float ov1 = __shfl_xor(v1, m);
            int oc1 = __shfl_xor(c1, m);
            float ov2 = __shfl_xor(v2, m);
            float mx = fmaxf(v1, ov1);
            v2 = fminf(fminf(v2, ov2), mx);
            bool take = (ov1 < v1) || (ov1 == v1 && oc1 < c1);
            v1 = take ? ov1 : v1;
            c1 = take ? oc1 : c1;
        }
        if (lx == 0) {
            const int rl = wm * 64 + (s >> 2) * 16 + quad * 4 + (s & 3);
            rvv[wn][rl] = v1; rcc[wn][rl] = c1; rv2s[wn][rl] = v2;
        }
    }
    __syncthreads();
    // merge the 4 wn column-groups; then fused margin-flag (was merge_flag)
    if (tid < 128) {
        float v1 = rvv[0][tid], v2 = rv2s[0][tid];
        int c1 = rcc[0][tid];
        #pragma unroll
        for (int q = 1; q < 4; ++q) {
            float ov1 = rvv[q][tid], ov2 = rv2s[q][tid];
            int oc1 = rcc[q][tid];
            float mx = fmaxf(v1, ov1);
            v2 = fminf(fminf(v2, ov2), mx);
            bool take = (ov1 < v1) || (ov1 == v1 && oc1 < c1);
            v1 = take ? ov1 : v1;
            c1 = take ? oc1 : c1;
        }
        const int row = arow_base + tid;
        out_idx[row] = (float)c1;
        if (v2 - v1 < TAU) {
            int slot = atomicAdd(flagcnt, 1);
            flaglist[slot] = row;           // cap 32768 = NROWS
            rkey[slot] = ~0ull;
            colidx[row] = -(slot + 1);      // sentinel: decode in fused_out
        } else {
            colidx[row] = c1;
        }
    }
}

// ---------- rescue: exact 3-term split GEMM over flagged rows ----------
// A' = [zhi|zhi|zlo], B' = [ehi|elo|ehi] (K=768) -- scored absmax=0
// full-problem. Grid (32, RSPLIT); idle blocks exit fast.
__launch_bounds__(256, 2)
__global__ void rescue_gemm(const unsigned short* __restrict__ zhi,
                            const unsigned short* __restrict__ zlo,
                            const unsigned short* __restrict__ ehi,
                            const unsigned short* __restrict__ elo,
                            const float* __restrict__ enrm,
                            const int* __restrict__ flagcnt,
                            const int* __restrict__ flaglist,
                            unsigned long long* __restrict__ rkey) {
    __shared__ __align__(16) unsigned short As[128 * 64];
    __shared__ __align__(16) unsigned short Bs[128 * 64];
    __shared__ float rv[2][128];
    __shared__ int   rc[2][128];

    const int count = *flagcnt;
    const int tid = threadIdx.x;
    const int w = tid >> 6, l = tid & 63;
    const int lx = l & 15, quad = l >> 4;
    const int wm = w >> 1, wn = w & 1;
    const int cs = blockIdx.y;                       // 0..RSPLIT-1
    const int cbase_cs = cs * (KCODES / RSPLIT);     // 512 cols per split

    const int st_row8 = l >> 3;
    const int st_g = (((l & 7) ^ (l >> 3)) * 8);
    const int fr_lx7 = lx & 7;

    for (int tb = blockIdx.x * 128; tb < count; tb += 32 * 128) {
        int arowj[4];
        #pragma unroll
        for (int j = 0; j < 4; ++j) {
            int li = tb + w * 32 + j * 8 + st_row8;
            arowj[j] = (li < count) ? flaglist[li] : 0;
        }

        float runv[16];
        int runc[16];
        #pragma unroll
        for (int s = 0; s < 16; ++s) { runv[s] = 3.0e38f; runc[s] = 0x7fffffff; }

        for (int nt = 0; nt < (KCODES / RSPLIT) / 128; ++nt) {   // 4 N-tiles
            const int colbase = cbase_cs + nt * 128;
            f32x4 acc[4][4];
            #pragma unroll
            for (int mi = 0; mi < 4; ++mi)
                #pragma unroll
                for (int ni = 0; ni < 4; ++ni) {
                    f32x4 zz = {0.f, 0.f, 0.f, 0.f};
                    acc[mi][ni] = zz;
                }

            #pragma unroll
            for (int seg = 0; seg < 3; ++seg) {
                const unsigned short* za = (seg == 2) ? zlo : zhi;
                const unsigned short* eb = (seg == 1) ? elo : ehi;
                for (int bk = 0; bk < 4; ++bk) {
                    const int ao = bk * 64;
                    __syncthreads();
                    #pragma unroll
                    for (int j = 0; j < 4; ++j) {
                        const int r = w * 32 + j * 8 + st_row8;
                        gload_lds16(za + (size_t)arowj[j] * DIM + ao + st_g,
                                    &As[(w * 32 + j * 8) * 64]);
                        gload_lds16(eb + (size_t)(colbase + r) * DIM + ao + st_g,
                                    &Bs[(w * 32 + j * 8) * 64]);
                    }
                    __syncthreads();
                    #pragma unroll
                    for (int kc = 0; kc < 2; ++kc) {
                        const int gsw = ((kc * 4 + quad) ^ fr_lx7) * 8;
                        v8h af[4], bfr[4];
                        #pragma unroll
                        for (int mi = 0; mi < 4; ++mi)
                            af[mi] = *(const v8h*)&As[(wm * 64 + mi * 16 + lx) * 64 + gsw];
                        #pragma unroll
                        for (int ni = 0; ni < 4; ++ni)
                            bfr[ni] = *(const v8h*)&Bs[(wn * 64 + ni * 16 + lx) * 64 + gsw];
                        #pragma unroll
                        for (int mi = 0; mi < 4; ++mi)
                            #pragma unroll
                            for (int ni = 0; ni < 4; ++ni)
                                acc[mi][ni] = __builtin_amdgcn_mfma_f32_16x16x32_f16(
                                    af[mi], bfr[ni], acc[mi][ni], 0, 0, 0);
                    }
                }
            }

            #pragma unroll
            for (int ni = 0; ni < 4; ++ni) {
                const int col = colbase + wn * 64 + ni * 16 + lx;
                const float es = enrm[col];
                #pragma unroll
                for (int mi = 0; mi < 4; ++mi)
                    #pragma unroll
                    for (int r = 0; r < 4; ++r) {
                        float sv = es - acc[mi][ni][r];
                        const int s = mi * 4 + r;
                        if (sv < runv[s]) { runv[s] = sv; runc[s] = col; }
                    }
            }
        }

        #pragma unroll
        for (int s = 0; s < 16; ++s) {
            float v = runv[s]; int c = runc[s];
            #pragma unroll
            for (int m = 1; m < 16; m <<= 1) {
                float ov = __shfl_xor(v, m);
                int oc = __shfl_xor(c, m);
                if (ov < v || (ov == v && oc < c)) { v = ov; c = oc; }
            }
            if (lx == 0) {
                const int mi = s >> 2, r = s & 3;
                const int rl = wm * 64 + mi * 16 + quad * 4 + r;
                rv[wn][rl] = v; rc[wn][rl] = c;
            }
        }
        __syncthreads();
        if (tid < 128) {
            float v0 = rv[0][tid]; int c0 = rc[0][tid];
            float v1 = rv[1][tid]; int c1 = rc[1][tid];
            if (v1 < v0 || (v1 == v0 && c1 < c0)) { v0 = v1; c0 = c1; }
            const int li = tb + tid;
            if (li < count) {
                unsigned long long key =
                    ((unsigned long long)fkey(v0) << 32) | (unsigned int)c0;
                atomicMin(&rkey[li], key);
            }
        }
        __syncthreads();
    }
}

// ---------- gather z_q, z_q_st, loss, histogram; decode rescued rows ----------
__global__ void fused_out(const int* __restrict__ colidx,
                          const unsigned long long* __restrict__ rkey,
                          const float* __restrict__ z,
                          const float* __restrict__ embed,
                          float* __restrict__ out_zq,
                          float* __restrict__ out_idx,
                          float* __restrict__ counts,
                          float* __restrict__ lossAcc) {
    __shared__ int cidx[16];
    const int tid = threadIdx.x;
    if (tid < 16) {
        const int row = blockIdx.x * 16 + tid;
        int c = colidx[row];
        if (c < 0) {                      // rescued row: decode packed key
            c = (int)(unsigned int)(rkey[-c - 1] & 0x1FFFull);
            out_idx[row] = (float)c;
        }
        cidx[tid] = c;
        atomicAdd(&counts[c], 1.0f);
    }
    __syncthreads();
    const int d = tid;
    float ls = 0.f;
    #pragma unroll 4
    for (int i = 0; i < 16; ++i) {
        const int row = blockIdx.x * 16 + i;
        const int c = cidx[i];
        const float zv = z[(size_t)row * DIM + d];
        const float ev = embed[(size_t)c * DIM + d];
        const float diff = ev - zv;
        out_zq[(size_t)row * DIM + d] = zv + diff;
        ls += diff * diff;
    }
    #pragma unroll
    for (int off = 32; off; off >>= 1) ls += __shfl_down(ls, off);
    __shared__ float ps[4];
    if ((tid & 63) == 0) ps[tid >> 6] = ls;
    __syncthreads();
    if (tid == 0) atomicAdd(lossAcc, ps[0] + ps[1] + ps[2] + ps[3]);
}

// ---------- loss scale + perplexity ----------
__global__ void finalize(const float* __restrict__ counts,
                         const float* __restrict__ lossAcc,
                         float* __restrict__ out_loss,
                         float* __restrict__ out_perp) {
    float h = 0.f;
    for (int k = threadIdx.x; k < KCODES; k += 256) {
        float p = counts[k] * (1.0f / (float)NROWS);
        h += p * logf(p + 1e-12f);
    }
    #pragma unroll
    for (int off = 32; off; off >>= 1) h += __shfl_down(h, off);
    __shared__ float ps[4];
    if ((threadIdx.x & 63) == 0) ps[threadIdx.x >> 6] = h;
    __syncthreads();
    if (threadIdx.x == 0) {
        *out_perp = expf(-(ps[0] + ps[1] + ps[2] + ps[3]));
        *out_loss = BETA * lossAcc[0] / (float)NELEM;
    }
}

extern "C" void kernel_launch(void* const* d_in, const int* in_sizes, int n_in,
                              void* d_out, int out_size, void* d_ws, size_t ws_size,
                              hipStream_t stream) {
    const float* z = (const float*)d_in[0];       // [32768, 256] f32
    const float* embed = (const float*)d_in[1];   // [8192, 256] f32
    char* ws = (char*)d_ws;

    // workspace layout (~44.1 MB; pval/pcol slots retired but offsets kept)
    unsigned short* zhi = (unsigned short*)(ws + 0);           // 16 MB
    unsigned short* zlo = (unsigned short*)(ws + 16777216);    // 16 MB
    unsigned short* ehi = (unsigned short*)(ws + 33554432);    // 4 MB
    unsigned short* elo = (unsigned short*)(ws + 37748736);    // 4 MB
    float* enrm    = (float*)(ws + 41943040);                  // 32 KB
    int*   colidx  = (int*)  (ws + 43548672);                  // 128 KB
    float* counts  = (float*)(ws + 43679744);                  // 32 KB
    float* lossAcc = (float*)(ws + 43712512);                  // 4 B
    int*   flagcnt = (int*)  (ws + 43712516);                  // 4 B
    int*   flaglist = (int*) (ws + 43712520);                  // 128 KB (8B-aligned end)
    unsigned long long* rkey = (unsigned long long*)(ws + 43843592); // 256 KB

    float* out = (float*)d_out;
    float* out_zq   = out;                 // 8388608
    float* out_loss = out + 8388608;       // 1
    float* out_perp = out + 8388609;       // 1
    float* out_idx  = out + 8388610;       // 32768 (indices as f32)

    // 5 dispatches (merge_flag fused into gemm_hi_fused epilogue)
    prep_all<<<16384, 256, 0, stream>>>(z, embed, zhi, zlo, ehi, elo, enrm,
                                        counts, lossAcc, flagcnt);
    gemm_hi_fused<<<NROWS / 128, 512, 0, stream>>>(
        zhi, ehi, enrm, colidx, out_idx, flagcnt, flaglist, rkey);
    rescue_gemm<<<dim3(32, RSPLIT), 256, 0, stream>>>(
        zhi, zlo, ehi, elo, enrm, flagcnt, flaglist, rkey);
    fused_out<<<NROWS / 16, 256, 0, stream>>>(colidx, rkey, z, embed,
                                              out_zq, out_idx, counts, lossAcc);
    finalize<<<1, 256, 0, stream>>>(counts, lossAcc, out_loss, out_perp);
}